// Round 2
// baseline (745.758 us; speedup 1.0000x reference)
//
#include <hip/hip_runtime.h>

// TemporalMambaBlock: B=2,T=16,H=W=28,C=192; D_inner=384, d_state=16, dt_rank=12, d_conv=4
#define NSEQ 1568
#define TDIM 16
#define CDIM 192
#define DIN  384
#define SDIM 16
#define RNK  12
#define XZW  768
#define DBLW 44
#define HW784 784

typedef unsigned short u16;
typedef unsigned int   u32;

__device__ __forceinline__ float bf2f(u16 u) {
  union { u32 i; float f; } c; c.i = ((u32)u) << 16; return c.f;
}
__device__ __forceinline__ float asf(u32 i) {
  union { u32 i; float f; } c; c.i = i; return c.f;
}
__device__ __forceinline__ u16 f2bf(float f) {   // round-to-nearest-even
  union { float f; u32 i; } c; c.f = f;
  u32 i = c.i;
  i += 0x7FFFu + ((i >> 16) & 1u);
  return (u16)(i >> 16);
}

// dtype-polymorphic global load/store
template<bool B16>
__device__ __forceinline__ float ldg(const void* p, int i) {
  if (B16) return bf2f(((const u16*)p)[i]);
  return ((const float*)p)[i];
}
template<bool B16>
__device__ __forceinline__ void stg(void* p, int i, float v) {
  if (B16) ((u16*)p)[i] = f2bf(v);
  else     ((float*)p)[i] = v;
}

struct Smem {
  float dt [TDIM*DIN];    // dt, then gated y (in-place)   24576 B
  float dbl[TDIM*DBLW];   // x_proj out: dt_low|B|C         2816 B
  u16   xs [TDIM*CDIM];   // input row (bf16)               6144 B
  u16   xn [TDIM*CDIM];   // rmsnormed                      6144 B
  u16   u  [TDIM*DIN];    // u, then uc (in-place)         12288 B
  u16   z  [TDIM*DIN];    // gate z                        12288 B
};                        // total 64,256 B -> fits 64 KiB, 2 blocks/CU

template<bool B16>
__device__ __forceinline__ void body(
    Smem& sm,
    const void* __restrict__ x,        const void* __restrict__ norm_w,
    const void* __restrict__ in_proj_w,const void* __restrict__ conv_w,
    const void* __restrict__ conv_b,   const void* __restrict__ x_proj_w,
    const void* __restrict__ dt_proj_w,const void* __restrict__ dt_proj_b,
    const void* __restrict__ A_log,    const void* __restrict__ Dp,
    const void* __restrict__ out_proj_w, void* __restrict__ out)
{
  const int tid = threadIdx.x;
  const int n  = blockIdx.x;
  const int b  = n / HW784;
  const int hw = n - b * HW784;

  // ---- 1. load xs: token (n,t) at x[((b*16+t)*784+hw)*192 + c] ----
  for (int i = tid; i < TDIM*CDIM; i += 384) {
    int t = i / CDIM, c = i - t * CDIM;
    sm.xs[i] = f2bf(ldg<B16>(x, ((b*TDIM + t)*HW784 + hw)*CDIM + c));
  }
  __syncthreads();

  // ---- 2. RMSNorm: wave per row, shuffle reduce ----
  {
    int wave = tid >> 6, lane = tid & 63;
    for (int t = wave; t < TDIM; t += 6) {
      float ss = 0.f;
      for (int c = lane; c < CDIM; c += 64) {
        float v = bf2f(sm.xs[t*CDIM + c]); ss += v*v;
      }
      #pragma unroll
      for (int off = 32; off > 0; off >>= 1) ss += __shfl_xor(ss, off, 64);
      float rs = rsqrtf(ss * (1.0f/CDIM) + 1e-6f);
      for (int c = lane; c < CDIM; c += 64)
        sm.xn[t*CDIM + c] = f2bf(bf2f(sm.xs[t*CDIM + c]) * rs * ldg<B16>(norm_w, c));
    }
  }
  __syncthreads();

  // ---- 3. in_proj: thread owns xz columns j0=2*tid, j0+1; all 16 t in regs ----
  {
    float acc0[TDIM], acc1[TDIM];
    #pragma unroll
    for (int t = 0; t < TDIM; ++t) { acc0[t] = 0.f; acc1[t] = 0.f; }
    const int j0 = 2 * tid;
    for (int c = 0; c < CDIM; c += 2) {
      float wA0 = ldg<B16>(in_proj_w,  c   *XZW + j0);
      float wA1 = ldg<B16>(in_proj_w,  c   *XZW + j0 + 1);
      float wB0 = ldg<B16>(in_proj_w, (c+1)*XZW + j0);
      float wB1 = ldg<B16>(in_proj_w, (c+1)*XZW + j0 + 1);
      #pragma unroll
      for (int t = 0; t < TDIM; ++t) {
        u32 xv = *(const u32*)(sm.xn + t*CDIM + c);   // xn[t][c], xn[t][c+1]
        float x0 = asf(xv << 16), x1 = asf(xv & 0xFFFF0000u);
        acc0[t] += x0*wA0 + x1*wB0;
        acc1[t] += x0*wA1 + x1*wB1;
      }
    }
    if (tid < 192) {          // u columns
      #pragma unroll
      for (int t = 0; t < TDIM; ++t) {
        sm.u[t*DIN + j0]   = f2bf(acc0[t]);
        sm.u[t*DIN + j0+1] = f2bf(acc1[t]);
      }
    } else {                  // z columns
      int z0 = j0 - 384;
      #pragma unroll
      for (int t = 0; t < TDIM; ++t) {
        sm.z[t*DIN + z0]   = f2bf(acc0[t]);
        sm.z[t*DIN + z0+1] = f2bf(acc1[t]);
      }
    }
  }
  __syncthreads();

  // ---- 4. causal depthwise conv (k=4) + SiLU, thread = channel d, in place ----
  {
    const int d = tid;
    float uv[TDIM];
    #pragma unroll
    for (int t = 0; t < TDIM; ++t) uv[t] = bf2f(sm.u[t*DIN + d]);
    float w0 = ldg<B16>(conv_w, d*4+0), w1 = ldg<B16>(conv_w, d*4+1);
    float w2 = ldg<B16>(conv_w, d*4+2), w3 = ldg<B16>(conv_w, d*4+3);
    float bias = ldg<B16>(conv_b, d);
    #pragma unroll
    for (int t = 0; t < TDIM; ++t) {
      float s = bias + uv[t]*w3;            // w[3] multiplies current step
      if (t >= 1) s += uv[t-1]*w2;
      if (t >= 2) s += uv[t-2]*w1;
      if (t >= 3) s += uv[t-3]*w0;
      float sg = 1.0f / (1.0f + __expf(-s));
      sm.u[t*DIN + d] = f2bf(s * sg);       // own column only: no race
    }
  }
  __syncthreads();

  // ---- 5. x_proj: 704 outputs (16 t x 44), <=2 per thread ----
  for (int o = tid; o < TDIM*DBLW; o += 384) {
    int t = o / DBLW, j = o - t*DBLW;
    float acc = 0.f;
    for (int d = 0; d < DIN; ++d)
      acc += bf2f(sm.u[t*DIN + d]) * ldg<B16>(x_proj_w, d*DBLW + j);
    sm.dbl[o] = acc;
  }
  __syncthreads();

  // ---- 6. dt_proj + softplus, thread = channel d ----
  {
    const int d = tid;
    float wd[RNK];
    #pragma unroll
    for (int r = 0; r < RNK; ++r) wd[r] = ldg<B16>(dt_proj_w, r*DIN + d);
    float bias = ldg<B16>(dt_proj_b, d);
    #pragma unroll
    for (int t = 0; t < TDIM; ++t) {
      float a = bias;
      #pragma unroll
      for (int r = 0; r < RNK; ++r) a += sm.dbl[t*DBLW + r] * wd[r];
      // stable softplus = max(a,0) + log1p(exp(-|a|))
      sm.dt[t*DIN + d] = fmaxf(a, 0.f) + log1pf(__expf(-fabsf(a)));
    }
  }
  __syncthreads();

  // ---- 7. selective scan + D skip + SiLU(z) gating, thread = channel d ----
  {
    const int d = tid;
    float A[SDIM], h[SDIM];
    #pragma unroll
    for (int s = 0; s < SDIM; ++s) {
      A[s] = -__expf(ldg<B16>(A_log, d*SDIM + s));
      h[s] = 0.f;
    }
    float Dv = ldg<B16>(Dp, d);
    for (int t = 0; t < TDIM; ++t) {
      float dtv = sm.dt[t*DIN + d];
      float uv  = bf2f(sm.u[t*DIN + d]);
      float du  = dtv * uv;
      float y = 0.f;
      #pragma unroll
      for (int s = 0; s < SDIM; ++s) {
        float dA = __expf(dtv * A[s]);
        h[s] = h[s]*dA + du * sm.dbl[t*DBLW + 12 + s];  // B_t[s]
        y += h[s] * sm.dbl[t*DBLW + 28 + s];            // C_t[s]
      }
      y += uv * Dv;
      float zv = bf2f(sm.z[t*DIN + d]);
      float sg = 1.0f / (1.0f + __expf(-zv));
      sm.dt[t*DIN + d] = y * (zv * sg);                 // overwrite own slot
    }
  }
  __syncthreads();

  // ---- 8. out_proj + residual: thread = (c, half of T) ----
  {
    const int tt = tid / CDIM;          // 0 -> t=0..7, 1 -> t=8..15
    const int c  = tid - tt*CDIM;
    float acc[8];
    #pragma unroll
    for (int i = 0; i < 8; ++i) acc[i] = 0.f;
    for (int d = 0; d < DIN; ++d) {
      float w = ldg<B16>(out_proj_w, d*CDIM + c);
      #pragma unroll
      for (int i = 0; i < 8; ++i)
        acc[i] += sm.dt[(tt*8 + i)*DIN + d] * w;        // broadcast read
    }
    #pragma unroll
    for (int i = 0; i < 8; ++i) {
      int t = tt*8 + i;
      float o = bf2f(sm.xs[t*CDIM + c]) + acc[i];
      stg<B16>(out, ((b*TDIM + t)*HW784 + hw)*CDIM + c, o);
    }
  }
}

__launch_bounds__(384)
__global__ void mamba_fused(
    const void* __restrict__ x,        const void* __restrict__ norm_w,
    const void* __restrict__ in_proj_w,const void* __restrict__ conv_w,
    const void* __restrict__ conv_b,   const void* __restrict__ x_proj_w,
    const void* __restrict__ dt_proj_w,const void* __restrict__ dt_proj_b,
    const void* __restrict__ A_log,    const void* __restrict__ Dp,
    const void* __restrict__ out_proj_w, void* __restrict__ out)
{
  __shared__ Smem sm;

  // ---- dtype probe (wave-uniform): bf16 data has plausible exponents at
  // even u16 slots; f32 data read as u16 gives uniform mantissa noise there.
  const u16* xu = (const u16*)x;
  int plaus = 0;
  #pragma unroll
  for (int k = 0; k < 32; ++k) {
    u16 v = xu[2*k];
    int e = (v >> 7) & 0xFF;
    plaus += ((e >= 100 && e <= 140) || v == 0) ? 1 : 0;
  }
  if (plaus >= 16)
    body<true >(sm, x, norm_w, in_proj_w, conv_w, conv_b, x_proj_w,
                dt_proj_w, dt_proj_b, A_log, Dp, out_proj_w, out);
  else
    body<false>(sm, x, norm_w, in_proj_w, conv_w, conv_b, x_proj_w,
                dt_proj_w, dt_proj_b, A_log, Dp, out_proj_w, out);
}

extern "C" void kernel_launch(void* const* d_in, const int* in_sizes, int n_in,
                              void* d_out, int out_size, void* d_ws, size_t ws_size,
                              hipStream_t stream) {
  mamba_fused<<<NSEQ, 384, 0, stream>>>(
      d_in[0],  // x
      d_in[1],  // norm_w
      d_in[2],  // in_proj_w (192x768)
      d_in[3],  // conv_w (384x4)
      d_in[4],  // conv_b
      d_in[5],  // x_proj_w (384x44)
      d_in[6],  // dt_proj_w (12x384)
      d_in[7],  // dt_proj_b
      d_in[8],  // A_log (384x16)
      d_in[9],  // D
      d_in[10], // out_proj_w (384x192)
      d_out);
}

// Round 3
// 244.200 us; speedup vs baseline: 3.0539x; 3.0539x over previous
//
#include <hip/hip_runtime.h>

// TemporalMambaBlock: B=2,T=16,H=W=28,C=192; D_inner=384, d_state=16, dt_rank=12, d_conv=4
#define NSEQ 1568
#define TDIM 16
#define CDIM 192
#define DIN  384
#define SDIM 16
#define RNK  12
#define XZW  768
#define DBLW 44
#define HW784 784

// padded LDS strides (halves): row stride mod 32 dwords == 4 -> conflict-free quads
#define XNP  200   // xn rows (192 + 8 pad)
#define DINP 392   // u / z rows (384 + 8 pad)
#define DBLP 48    // dbl rows (44 padded to 48, f32)

// packed-weight tiling
#define NT_IN 48
#define KT_IN 6
#define NT_OUT 12
#define KT_OUT 12
#define NT_XP 3
#define KT_XP 12
#define GRP_IN  (NT_IN*KT_IN*64)    // 18432 groups of 8
#define GRP_OUT (NT_OUT*KT_OUT*64)  // 9216
#define GRP_XP  (NT_XP*KT_XP*64)    // 2304
#define OFF_OUT (GRP_IN*8)          // elem offsets in ws
#define OFF_XP  (OFF_OUT + GRP_OUT*8)
#define WS_NEED ((size_t)(OFF_XP + GRP_XP*8) * 2)  // bytes = 479232

typedef unsigned short u16;
typedef unsigned int   u32;
typedef __attribute__((ext_vector_type(8))) short short8;
typedef __attribute__((ext_vector_type(4))) float f32x4;

__device__ __forceinline__ float bf2f(u16 u) {
  union { u32 i; float f; } c; c.i = ((u32)u) << 16; return c.f;
}
__device__ __forceinline__ float asf(u32 i) {
  union { u32 i; float f; } c; c.i = i; return c.f;
}
__device__ __forceinline__ u16 f2bf(float f) {   // round-to-nearest-even
  union { float f; u32 i; } c; c.f = f;
  u32 i = c.i;
  i += 0x7FFFu + ((i >> 16) & 1u);
  return (u16)(i >> 16);
}

template<bool B16>
__device__ __forceinline__ float ldg(const void* p, int i) {
  if (B16) return bf2f(((const u16*)p)[i]);
  return ((const float*)p)[i];
}
template<bool B16>
__device__ __forceinline__ void stg(void* p, int i, float v) {
  if (B16) ((u16*)p)[i] = f2bf(v);
  else     ((float*)p)[i] = v;
}

// dtype probe: bf16 data has plausible exponents at even u16 slots; f32 read
// as u16 gives mantissa noise. (Round-2 evidence: selects f32 here.)
__device__ __forceinline__ bool probe_bf16(const void* x) {
  const u16* xu = (const u16*)x;
  int plaus = 0;
  #pragma unroll
  for (int k = 0; k < 32; ++k) {
    u16 v = xu[2*k];
    int e = (v >> 7) & 0xFF;
    plaus += ((e >= 100 && e <= 140) || v == 0) ? 1 : 0;
  }
  return plaus >= 16;
}

// ---------------- weight packing: B-fragment order for mfma 16x16x32 --------
// packed[((nt*KT + kt)*64 + lane)*8 + j] = W[kt*32 + (lane>>4)*8 + j][nt*16 + (lane&15)]
template<bool B16>
__device__ __forceinline__ void pack_body(const void* in_w, const void* out_w,
                                          const void* xp_w, u16* ws, int g) {
  if (g < GRP_IN) {
    int lane = g & 63, kt = (g >> 6) % KT_IN, nt = g / (64*KT_IN);
    int k0 = kt*32 + (lane >> 4)*8, n = nt*16 + (lane & 15);
    u16* dst = ws + g*8;
    #pragma unroll
    for (int j = 0; j < 8; ++j) dst[j] = f2bf(ldg<B16>(in_w, (k0+j)*XZW + n));
  } else if (g < GRP_IN + GRP_OUT) {
    int gg = g - GRP_IN;
    int lane = gg & 63, kt = (gg >> 6) % KT_OUT, nt = gg / (64*KT_OUT);
    int k0 = kt*32 + (lane >> 4)*8, n = nt*16 + (lane & 15);
    u16* dst = ws + OFF_OUT + gg*8;
    #pragma unroll
    for (int j = 0; j < 8; ++j) dst[j] = f2bf(ldg<B16>(out_w, (k0+j)*CDIM + n));
  } else if (g < GRP_IN + GRP_OUT + GRP_XP) {
    int gg = g - GRP_IN - GRP_OUT;
    int lane = gg & 63, kt = (gg >> 6) % KT_XP, nt = gg / (64*KT_XP);
    int k0 = kt*32 + (lane >> 4)*8, n = nt*16 + (lane & 15);
    u16* dst = ws + OFF_XP + gg*8;
    #pragma unroll
    for (int j = 0; j < 8; ++j)
      dst[j] = f2bf(n < DBLW ? ldg<B16>(xp_w, (k0+j)*DBLW + n) : 0.f);
  }
}

__global__ void pack_w(const void* __restrict__ x, const void* __restrict__ in_w,
                       const void* __restrict__ out_w, const void* __restrict__ xp_w,
                       u16* __restrict__ ws) {
  int g = blockIdx.x * blockDim.x + threadIdx.x;
  if (probe_bf16(x)) pack_body<true >(in_w, out_w, xp_w, ws, g);
  else               pack_body<false>(in_w, out_w, xp_w, ws, g);
}

// ---------------- fused MFMA kernel -----------------------------------------
struct Smem {
  u16   xs [TDIM*CDIM];   // input row (bf16)              6144 B
  u16   xn [TDIM*XNP];    // rmsnormed, padded             6400 B
  u16   u  [TDIM*DINP];   // u -> uc (in-place), padded   12544 B
  u16   z  [TDIM*DINP];   // z -> gated y (in-place)      12544 B
  u16   dtb[TDIM*DIN];    // dt (bf16)                    12288 B
  float dbl[TDIM*DBLP];   // x_proj out: dt_low|B|C        3072 B
};                        // total 52,992 B -> 3 blocks/CU possible

template<bool B16>
__device__ __forceinline__ void body(
    Smem& sm, const u16* __restrict__ ws,
    const void* __restrict__ x,        const void* __restrict__ norm_w,
    const void* __restrict__ conv_w,   const void* __restrict__ conv_b,
    const void* __restrict__ dt_proj_w,const void* __restrict__ dt_proj_b,
    const void* __restrict__ A_log,    const void* __restrict__ Dp,
    void* __restrict__ out)
{
  const int tid  = threadIdx.x;
  const int wid  = tid >> 6;
  const int lane = tid & 63;
  const int quad = lane >> 4;
  const int l16  = lane & 15;
  const int n  = blockIdx.x;
  const int b  = n / HW784;
  const int hw = n - b * HW784;

  // ---- 1. load xs ----
  for (int i = tid; i < TDIM*CDIM; i += 384) {
    int t = i / CDIM, c = i - t * CDIM;
    sm.xs[i] = f2bf(ldg<B16>(x, ((b*TDIM + t)*HW784 + hw)*CDIM + c));
  }
  __syncthreads();

  // ---- 2. RMSNorm: wave per row -> sm.xn (padded rows) ----
  for (int t = wid; t < TDIM; t += 6) {
    float ss = 0.f;
    for (int c = lane; c < CDIM; c += 64) {
      float v = bf2f(sm.xs[t*CDIM + c]); ss += v*v;
    }
    #pragma unroll
    for (int off = 32; off > 0; off >>= 1) ss += __shfl_xor(ss, off, 64);
    float rs = rsqrtf(ss * (1.0f/CDIM) + 1e-6f);
    for (int c = lane; c < CDIM; c += 64)
      sm.xn[t*XNP + c] = f2bf(bf2f(sm.xs[t*CDIM + c]) * rs * ldg<B16>(norm_w, c));
  }
  __syncthreads();

  // ---- 3. in_proj via MFMA: wave w -> col tiles w*8..w*8+7 ----
  {
    short8 afr[KT_IN];
    #pragma unroll
    for (int kt = 0; kt < KT_IN; ++kt)
      afr[kt] = *(const short8*)(sm.xn + l16*XNP + kt*32 + quad*8);
    f32x4 acc[8];
    #pragma unroll
    for (int i = 0; i < 8; ++i) acc[i] = (f32x4)0.f;
    #pragma unroll
    for (int i = 0; i < 8; ++i) {
      int ntg = wid*8 + i;
      #pragma unroll
      for (int kt = 0; kt < KT_IN; ++kt) {
        short8 bfr = *(const short8*)(ws + ((ntg*KT_IN + kt)*64 + lane)*8);
        acc[i] = __builtin_amdgcn_mfma_f32_16x16x32_bf16(afr[kt], bfr, acc[i], 0, 0, 0);
      }
    }
    #pragma unroll
    for (int i = 0; i < 8; ++i) {
      int ntg = wid*8 + i;
      u16* dst = (ntg < 24) ? sm.u : sm.z;
      int col = ((ntg < 24) ? ntg*16 : (ntg-24)*16) + l16;
      #pragma unroll
      for (int r = 0; r < 4; ++r)
        dst[(quad*4 + r)*DINP + col] = f2bf(acc[i][r]);
    }
  }
  __syncthreads();

  // ---- 4. causal depthwise conv (k=4) + SiLU, thread = channel d ----
  {
    const int d = tid;
    float uv[TDIM];
    #pragma unroll
    for (int t = 0; t < TDIM; ++t) uv[t] = bf2f(sm.u[t*DINP + d]);
    float w0 = ldg<B16>(conv_w, d*4+0), w1 = ldg<B16>(conv_w, d*4+1);
    float w2 = ldg<B16>(conv_w, d*4+2), w3 = ldg<B16>(conv_w, d*4+3);
    float bias = ldg<B16>(conv_b, d);
    #pragma unroll
    for (int t = 0; t < TDIM; ++t) {
      float s = bias + uv[t]*w3;
      if (t >= 1) s += uv[t-1]*w2;
      if (t >= 2) s += uv[t-2]*w1;
      if (t >= 3) s += uv[t-3]*w0;
      float sg = 1.0f / (1.0f + __expf(-s));
      sm.u[t*DINP + d] = f2bf(s * sg);
    }
  }
  __syncthreads();

  // ---- 5. x_proj via MFMA: waves 0..2, one 16-col tile each ----
  if (wid < 3) {
    f32x4 acc = (f32x4)0.f;
    #pragma unroll
    for (int kt = 0; kt < KT_XP; ++kt) {
      short8 afr = *(const short8*)(sm.u + l16*DINP + kt*32 + quad*8);
      short8 bfr = *(const short8*)(ws + OFF_XP + ((wid*KT_XP + kt)*64 + lane)*8);
      acc = __builtin_amdgcn_mfma_f32_16x16x32_bf16(afr, bfr, acc, 0, 0, 0);
    }
    #pragma unroll
    for (int r = 0; r < 4; ++r)
      sm.dbl[(quad*4 + r)*DBLP + wid*16 + l16] = acc[r];
  }
  __syncthreads();

  // ---- 6. dt_proj + softplus, thread = channel d -> bf16 dt ----
  {
    const int d = tid;
    float wd[RNK];
    #pragma unroll
    for (int r = 0; r < RNK; ++r) wd[r] = ldg<B16>(dt_proj_w, r*DIN + d);
    float bias = ldg<B16>(dt_proj_b, d);
    #pragma unroll
    for (int t = 0; t < TDIM; ++t) {
      float a = bias;
      #pragma unroll
      for (int r = 0; r < RNK; ++r) a += sm.dbl[t*DBLP + r] * wd[r];
      float sp = fmaxf(a, 0.f) + log1pf(__expf(-fabsf(a)));
      sm.dtb[t*DIN + d] = f2bf(sp);
    }
  }
  __syncthreads();

  // ---- 7. selective scan + D skip + SiLU(z) gating, thread = channel d ----
  {
    const int d = tid;
    float A[SDIM], h[SDIM];
    #pragma unroll
    for (int s = 0; s < SDIM; ++s) {
      A[s] = -__expf(ldg<B16>(A_log, d*SDIM + s));
      h[s] = 0.f;
    }
    float Dv = ldg<B16>(Dp, d);
    for (int t = 0; t < TDIM; ++t) {
      float dtv = bf2f(sm.dtb[t*DIN + d]);
      float uv  = bf2f(sm.u[t*DINP + d]);
      float du  = dtv * uv;
      float y = 0.f;
      #pragma unroll
      for (int s = 0; s < SDIM; ++s) {
        float dA = __expf(dtv * A[s]);
        h[s] = h[s]*dA + du * sm.dbl[t*DBLP + 12 + s];  // B_t[s]
        y += h[s] * sm.dbl[t*DBLP + 28 + s];            // C_t[s]
      }
      y += uv * Dv;
      float zv = bf2f(sm.z[t*DINP + d]);
      float sg = 1.0f / (1.0f + __expf(-zv));
      sm.z[t*DINP + d] = f2bf(y * (zv * sg));           // gated y, in place
    }
  }
  __syncthreads();

  // ---- 8. out_proj via MFMA + residual: wave w -> col tiles w*2, w*2+1 ----
  {
    f32x4 acc[2];
    acc[0] = (f32x4)0.f; acc[1] = (f32x4)0.f;
    #pragma unroll
    for (int kt = 0; kt < KT_OUT; ++kt) {
      short8 afr = *(const short8*)(sm.z + l16*DINP + kt*32 + quad*8);
      #pragma unroll
      for (int i = 0; i < 2; ++i) {
        int ntg = wid*2 + i;
        short8 bfr = *(const short8*)(ws + OFF_OUT + ((ntg*KT_OUT + kt)*64 + lane)*8);
        acc[i] = __builtin_amdgcn_mfma_f32_16x16x32_bf16(afr, bfr, acc[i], 0, 0, 0);
      }
    }
    #pragma unroll
    for (int i = 0; i < 2; ++i) {
      int col = (wid*2 + i)*16 + l16;
      #pragma unroll
      for (int r = 0; r < 4; ++r) {
        int row = quad*4 + r;
        float o = bf2f(sm.xs[row*CDIM + col]) + acc[i][r];
        stg<B16>(out, ((b*TDIM + row)*HW784 + hw)*CDIM + col, o);
      }
    }
  }
}

__launch_bounds__(384)
__global__ void mamba_mfma(
    const u16* __restrict__ ws,
    const void* __restrict__ x,        const void* __restrict__ norm_w,
    const void* __restrict__ conv_w,   const void* __restrict__ conv_b,
    const void* __restrict__ dt_proj_w,const void* __restrict__ dt_proj_b,
    const void* __restrict__ A_log,    const void* __restrict__ Dp,
    void* __restrict__ out)
{
  __shared__ Smem sm;
  if (probe_bf16(x))
    body<true >(sm, ws, x, norm_w, conv_w, conv_b, dt_proj_w, dt_proj_b, A_log, Dp, out);
  else
    body<false>(sm, ws, x, norm_w, conv_w, conv_b, dt_proj_w, dt_proj_b, A_log, Dp, out);
}

// ---------------- fallback (round-2 kernel, no ws needed) -------------------
struct SmemF {
  float dt [TDIM*DIN];
  float dbl[TDIM*DBLW];
  u16   xs [TDIM*CDIM];
  u16   xn [TDIM*CDIM];
  u16   u  [TDIM*DIN];
  u16   z  [TDIM*DIN];
};

template<bool B16>
__device__ __forceinline__ void body_fb(
    SmemF& sm,
    const void* __restrict__ x,        const void* __restrict__ norm_w,
    const void* __restrict__ in_proj_w,const void* __restrict__ conv_w,
    const void* __restrict__ conv_b,   const void* __restrict__ x_proj_w,
    const void* __restrict__ dt_proj_w,const void* __restrict__ dt_proj_b,
    const void* __restrict__ A_log,    const void* __restrict__ Dp,
    const void* __restrict__ out_proj_w, void* __restrict__ out)
{
  const int tid = threadIdx.x;
  const int n  = blockIdx.x;
  const int b  = n / HW784;
  const int hw = n - b * HW784;

  for (int i = tid; i < TDIM*CDIM; i += 384) {
    int t = i / CDIM, c = i - t * CDIM;
    sm.xs[i] = f2bf(ldg<B16>(x, ((b*TDIM + t)*HW784 + hw)*CDIM + c));
  }
  __syncthreads();
  {
    int wave = tid >> 6, lane = tid & 63;
    for (int t = wave; t < TDIM; t += 6) {
      float ss = 0.f;
      for (int c = lane; c < CDIM; c += 64) {
        float v = bf2f(sm.xs[t*CDIM + c]); ss += v*v;
      }
      #pragma unroll
      for (int off = 32; off > 0; off >>= 1) ss += __shfl_xor(ss, off, 64);
      float rs = rsqrtf(ss * (1.0f/CDIM) + 1e-6f);
      for (int c = lane; c < CDIM; c += 64)
        sm.xn[t*CDIM + c] = f2bf(bf2f(sm.xs[t*CDIM + c]) * rs * ldg<B16>(norm_w, c));
    }
  }
  __syncthreads();
  {
    float acc0[TDIM], acc1[TDIM];
    #pragma unroll
    for (int t = 0; t < TDIM; ++t) { acc0[t] = 0.f; acc1[t] = 0.f; }
    const int j0 = 2 * tid;
    for (int c = 0; c < CDIM; c += 2) {
      float wA0 = ldg<B16>(in_proj_w,  c   *XZW + j0);
      float wA1 = ldg<B16>(in_proj_w,  c   *XZW + j0 + 1);
      float wB0 = ldg<B16>(in_proj_w, (c+1)*XZW + j0);
      float wB1 = ldg<B16>(in_proj_w, (c+1)*XZW + j0 + 1);
      #pragma unroll
      for (int t = 0; t < TDIM; ++t) {
        u32 xv = *(const u32*)(sm.xn + t*CDIM + c);
        float x0 = asf(xv << 16), x1 = asf(xv & 0xFFFF0000u);
        acc0[t] += x0*wA0 + x1*wB0;
        acc1[t] += x0*wA1 + x1*wB1;
      }
    }
    if (tid < 192) {
      #pragma unroll
      for (int t = 0; t < TDIM; ++t) {
        sm.u[t*DIN + j0]   = f2bf(acc0[t]);
        sm.u[t*DIN + j0+1] = f2bf(acc1[t]);
      }
    } else {
      int z0 = j0 - 384;
      #pragma unroll
      for (int t = 0; t < TDIM; ++t) {
        sm.z[t*DIN + z0]   = f2bf(acc0[t]);
        sm.z[t*DIN + z0+1] = f2bf(acc1[t]);
      }
    }
  }
  __syncthreads();
  {
    const int d = tid;
    float uv[TDIM];
    #pragma unroll
    for (int t = 0; t < TDIM; ++t) uv[t] = bf2f(sm.u[t*DIN + d]);
    float w0 = ldg<B16>(conv_w, d*4+0), w1 = ldg<B16>(conv_w, d*4+1);
    float w2 = ldg<B16>(conv_w, d*4+2), w3 = ldg<B16>(conv_w, d*4+3);
    float bias = ldg<B16>(conv_b, d);
    #pragma unroll
    for (int t = 0; t < TDIM; ++t) {
      float s = bias + uv[t]*w3;
      if (t >= 1) s += uv[t-1]*w2;
      if (t >= 2) s += uv[t-2]*w1;
      if (t >= 3) s += uv[t-3]*w0;
      float sg = 1.0f / (1.0f + __expf(-s));
      sm.u[t*DIN + d] = f2bf(s * sg);
    }
  }
  __syncthreads();
  for (int o = tid; o < TDIM*DBLW; o += 384) {
    int t = o / DBLW, j = o - t*DBLW;
    float acc = 0.f;
    for (int d = 0; d < DIN; ++d)
      acc += bf2f(sm.u[t*DIN + d]) * ldg<B16>(x_proj_w, d*DBLW + j);
    sm.dbl[o] = acc;
  }
  __syncthreads();
  {
    const int d = tid;
    float wd[RNK];
    #pragma unroll
    for (int r = 0; r < RNK; ++r) wd[r] = ldg<B16>(dt_proj_w, r*DIN + d);
    float bias = ldg<B16>(dt_proj_b, d);
    #pragma unroll
    for (int t = 0; t < TDIM; ++t) {
      float a = bias;
      #pragma unroll
      for (int r = 0; r < RNK; ++r) a += sm.dbl[t*DBLW + r] * wd[r];
      sm.dt[t*DIN + d] = fmaxf(a, 0.f) + log1pf(__expf(-fabsf(a)));
    }
  }
  __syncthreads();
  {
    const int d = tid;
    float A[SDIM], h[SDIM];
    #pragma unroll
    for (int s = 0; s < SDIM; ++s) {
      A[s] = -__expf(ldg<B16>(A_log, d*SDIM + s));
      h[s] = 0.f;
    }
    float Dv = ldg<B16>(Dp, d);
    for (int t = 0; t < TDIM; ++t) {
      float dtv = sm.dt[t*DIN + d];
      float uv  = bf2f(sm.u[t*DIN + d]);
      float du  = dtv * uv;
      float y = 0.f;
      #pragma unroll
      for (int s = 0; s < SDIM; ++s) {
        float dA = __expf(dtv * A[s]);
        h[s] = h[s]*dA + du * sm.dbl[t*DBLW + 12 + s];
        y += h[s] * sm.dbl[t*DBLW + 28 + s];
      }
      y += uv * Dv;
      float zv = bf2f(sm.z[t*DIN + d]);
      float sg = 1.0f / (1.0f + __expf(-zv));
      sm.dt[t*DIN + d] = y * (zv * sg);
    }
  }
  __syncthreads();
  {
    const int tt = tid / CDIM;
    const int c  = tid - tt*CDIM;
    float acc[8];
    #pragma unroll
    for (int i = 0; i < 8; ++i) acc[i] = 0.f;
    for (int d = 0; d < DIN; ++d) {
      float w = ldg<B16>(out_proj_w, d*CDIM + c);
      #pragma unroll
      for (int i = 0; i < 8; ++i)
        acc[i] += sm.dt[(tt*8 + i)*DIN + d] * w;
    }
    #pragma unroll
    for (int i = 0; i < 8; ++i) {
      int t = tt*8 + i;
      float o = bf2f(sm.xs[t*CDIM + c]) + acc[i];
      stg<B16>(out, ((b*TDIM + t)*HW784 + hw)*CDIM + c, o);
    }
  }
}

__launch_bounds__(384)
__global__ void mamba_fallback(
    const void* __restrict__ x,        const void* __restrict__ norm_w,
    const void* __restrict__ in_proj_w,const void* __restrict__ conv_w,
    const void* __restrict__ conv_b,   const void* __restrict__ x_proj_w,
    const void* __restrict__ dt_proj_w,const void* __restrict__ dt_proj_b,
    const void* __restrict__ A_log,    const void* __restrict__ Dp,
    const void* __restrict__ out_proj_w, void* __restrict__ out)
{
  __shared__ SmemF sm;
  if (probe_bf16(x))
    body_fb<true >(sm, x, norm_w, in_proj_w, conv_w, conv_b, x_proj_w,
                   dt_proj_w, dt_proj_b, A_log, Dp, out_proj_w, out);
  else
    body_fb<false>(sm, x, norm_w, in_proj_w, conv_w, conv_b, x_proj_w,
                   dt_proj_w, dt_proj_b, A_log, Dp, out_proj_w, out);
}

extern "C" void kernel_launch(void* const* d_in, const int* in_sizes, int n_in,
                              void* d_out, int out_size, void* d_ws, size_t ws_size,
                              hipStream_t stream) {
  if (ws_size >= WS_NEED) {
    int packThreads = GRP_IN + GRP_OUT + GRP_XP;
    pack_w<<<(packThreads + 255) / 256, 256, 0, stream>>>(
        d_in[0], d_in[2], d_in[10], d_in[5], (u16*)d_ws);
    mamba_mfma<<<NSEQ, 384, 0, stream>>>(
        (const u16*)d_ws,
        d_in[0], d_in[1], d_in[3], d_in[4],
        d_in[6], d_in[7], d_in[8], d_in[9], d_out);
  } else {
    mamba_fallback<<<NSEQ, 384, 0, stream>>>(
        d_in[0], d_in[1], d_in[2], d_in[3], d_in[4], d_in[5],
        d_in[6], d_in[7], d_in[8], d_in[9], d_in[10], d_out);
  }
}

// Round 4
// 185.855 us; speedup vs baseline: 4.0126x; 1.3139x over previous
//
#include <hip/hip_runtime.h>

// TemporalMambaBlock: B=2,T=16,H=W=28,C=192; D_inner=384, d_state=16, dt_rank=12, d_conv=4
#define NSEQ 1568
#define TDIM 16
#define CDIM 192
#define DIN  384
#define SDIM 16
#define RNK  12
#define XZW  768
#define DBLW 44
#define HW784 784

// padded LDS strides (halves): row stride dwords mod 32 == 4 -> b128 quad reads 2-way (free),
// and row byte-stride % 16 == 0 keeps ds_read_b128 aligned.
#define XNP  200   // xn rows (192 + 8 pad)  -> 400 B
#define DINP 392   // u / z rows (384 + 8)   -> 784 B
#define DBLP 48    // dbl rows (44 -> 48, f32)

// packed-weight tiling (B-fragment order for mfma_f32_16x16x32_bf16)
#define NT_IN 48
#define KT_IN 6
#define NT_OUT 12
#define KT_OUT 12
#define NT_XP 3
#define KT_XP 12
#define GRP_IN  (NT_IN*KT_IN*64)    // 18432 groups of 8
#define GRP_OUT (NT_OUT*KT_OUT*64)  // 9216
#define GRP_XP  (NT_XP*KT_XP*64)    // 2304
#define OFF_OUT (GRP_IN*8)
#define OFF_XP  (OFF_OUT + GRP_OUT*8)
#define WS_NEED ((size_t)(OFF_XP + GRP_XP*8) * 2)  // 479232 bytes

typedef unsigned short u16;
typedef unsigned int   u32;
typedef __attribute__((ext_vector_type(8))) short short8;
typedef __attribute__((ext_vector_type(4))) float f32x4;

#define LOG2E 1.44269504f
#define LN2   0.69314718f

__device__ __forceinline__ float bf2f(u16 u) {
  union { u32 i; float f; } c; c.i = ((u32)u) << 16; return c.f;
}
__device__ __forceinline__ float asf(u32 i) {
  union { u32 i; float f; } c; c.i = i; return c.f;
}
__device__ __forceinline__ u16 f2bf(float f) {   // round-to-nearest-even
  union { float f; u32 i; } c; c.f = f;
  u32 i = c.i;
  i += 0x7FFFu + ((i >> 16) & 1u);
  return (u16)(i >> 16);
}

// raw transcendental units (v_exp_f32 / v_log_f32 / v_rcp_f32)
__device__ __forceinline__ float ex2(float x) {
#if __has_builtin(__builtin_amdgcn_exp2f)
  return __builtin_amdgcn_exp2f(x);
#else
  return exp2f(x);
#endif
}
__device__ __forceinline__ float lg2(float x) {
#if __has_builtin(__builtin_amdgcn_logf)
  return __builtin_amdgcn_logf(x);
#else
  return log2f(x);
#endif
}
__device__ __forceinline__ float frcp(float x) {
#if __has_builtin(__builtin_amdgcn_rcpf)
  return __builtin_amdgcn_rcpf(x);
#else
  return 1.0f / x;
#endif
}
__device__ __forceinline__ float sigmoid_f(float s) {       // 1/(1+e^-s)
  return frcp(1.0f + ex2(-LOG2E * s));
}
__device__ __forceinline__ float softplus_f(float a) {      // log(1+e^a), stable
  return fmaxf(a, 0.f) + LN2 * lg2(1.0f + ex2(-LOG2E * fabsf(a)));
}

template<bool B16>
__device__ __forceinline__ float ldg(const void* p, int i) {
  if (B16) return bf2f(((const u16*)p)[i]);
  return ((const float*)p)[i];
}
template<bool B16>
__device__ __forceinline__ void stg(void* p, int i, float v) {
  if (B16) ((u16*)p)[i] = f2bf(v);
  else     ((float*)p)[i] = v;
}

// dtype probe: bf16 data has plausible exponents at even u16 slots; f32 read
// as u16 gives mantissa noise. (Round-2/3 evidence: selects the f32 path.)
__device__ __forceinline__ bool probe_bf16(const void* x) {
  const u16* xu = (const u16*)x;
  int plaus = 0;
  #pragma unroll
  for (int k = 0; k < 32; ++k) {
    u16 v = xu[2*k];
    int e = (v >> 7) & 0xFF;
    plaus += ((e >= 100 && e <= 140) || v == 0) ? 1 : 0;
  }
  return plaus >= 16;
}

// ---------------- weight packing: B-fragment order for mfma 16x16x32 --------
// packed[((nt*KT + kt)*64 + lane)*8 + j] = W[kt*32 + (lane>>4)*8 + j][nt*16 + (lane&15)]
template<bool B16>
__device__ __forceinline__ void pack_body(const void* in_w, const void* out_w,
                                          const void* xp_w, u16* ws, int g) {
  if (g < GRP_IN) {
    int lane = g & 63, kt = (g >> 6) % KT_IN, nt = g / (64*KT_IN);
    int k0 = kt*32 + (lane >> 4)*8, n = nt*16 + (lane & 15);
    u16* dst = ws + g*8;
    #pragma unroll
    for (int j = 0; j < 8; ++j) dst[j] = f2bf(ldg<B16>(in_w, (k0+j)*XZW + n));
  } else if (g < GRP_IN + GRP_OUT) {
    int gg = g - GRP_IN;
    int lane = gg & 63, kt = (gg >> 6) % KT_OUT, nt = gg / (64*KT_OUT);
    int k0 = kt*32 + (lane >> 4)*8, n = nt*16 + (lane & 15);
    u16* dst = ws + OFF_OUT + gg*8;
    #pragma unroll
    for (int j = 0; j < 8; ++j) dst[j] = f2bf(ldg<B16>(out_w, (k0+j)*CDIM + n));
  } else if (g < GRP_IN + GRP_OUT + GRP_XP) {
    int gg = g - GRP_IN - GRP_OUT;
    int lane = gg & 63, kt = (gg >> 6) % KT_XP, nt = gg / (64*KT_XP);
    int k0 = kt*32 + (lane >> 4)*8, n = nt*16 + (lane & 15);
    u16* dst = ws + OFF_XP + gg*8;
    #pragma unroll
    for (int j = 0; j < 8; ++j)
      dst[j] = f2bf(n < DBLW ? ldg<B16>(xp_w, (k0+j)*DBLW + n) : 0.f);
  }
}

__global__ void pack_w(const void* __restrict__ x, const void* __restrict__ in_w,
                       const void* __restrict__ out_w, const void* __restrict__ xp_w,
                       u16* __restrict__ ws) {
  int g = blockIdx.x * blockDim.x + threadIdx.x;
  if (probe_bf16(x)) pack_body<true >(in_w, out_w, xp_w, ws, g);
  else               pack_body<false>(in_w, out_w, xp_w, ws, g);
}

// ---------------- fused MFMA kernel -----------------------------------------
struct Smem {
  u16   xn [TDIM*XNP];    // rmsnormed, padded             6400 B
  u16   u  [TDIM*DINP];   // u -> uc (in-place), padded   12544 B
  u16   z  [TDIM*DINP];   // z -> gated y (in-place)      12544 B
  float dbl[TDIM*DBLP];   // x_proj out: dt_low|B|C        3072 B
};                        // total 34,560 B -> 4 blocks/CU

template<bool B16>
__device__ __forceinline__ void body(
    Smem& sm, const u16* __restrict__ ws,
    const void* __restrict__ x,        const void* __restrict__ norm_w,
    const void* __restrict__ conv_w,   const void* __restrict__ conv_b,
    const void* __restrict__ dt_proj_w,const void* __restrict__ dt_proj_b,
    const void* __restrict__ A_log,    const void* __restrict__ Dp,
    void* __restrict__ out)
{
  const int tid  = threadIdx.x;
  const int wid  = tid >> 6;
  const int lane = tid & 63;
  const int quad = lane >> 4;
  const int l16  = lane & 15;
  const int n  = blockIdx.x;
  const int b  = n / HW784;
  const int hw = n - b * HW784;

  // ---- P1: RMSNorm straight from global (192 = 3 x 64 lanes) -> xn ----
  {
    const int c0 = lane, c1 = lane + 64, c2 = lane + 128;
    float nw0 = ldg<B16>(norm_w, c0), nw1 = ldg<B16>(norm_w, c1), nw2 = ldg<B16>(norm_w, c2);
    for (int t = wid; t < TDIM; t += 6) {
      int base = ((b*TDIM + t)*HW784 + hw)*CDIM;
      float v0 = ldg<B16>(x, base + c0);
      float v1 = ldg<B16>(x, base + c1);
      float v2 = ldg<B16>(x, base + c2);
      float ss = v0*v0 + v1*v1 + v2*v2;
      #pragma unroll
      for (int off = 32; off > 0; off >>= 1) ss += __shfl_xor(ss, off, 64);
      float rs = rsqrtf(ss * (1.0f/CDIM) + 1e-6f);
      sm.xn[t*XNP + c0] = f2bf(v0 * rs * nw0);
      sm.xn[t*XNP + c1] = f2bf(v1 * rs * nw1);
      sm.xn[t*XNP + c2] = f2bf(v2 * rs * nw2);
    }
  }
  __syncthreads();

  // ---- P2: in_proj via MFMA: wave w -> col tiles w*8..w*8+7 (2 groups of 4) ----
  {
    short8 afr[KT_IN];
    #pragma unroll
    for (int kt = 0; kt < KT_IN; ++kt)
      afr[kt] = *(const short8*)(sm.xn + l16*XNP + kt*32 + quad*8);
    #pragma unroll
    for (int g = 0; g < 2; ++g) {
      f32x4 acc[4];
      #pragma unroll
      for (int i = 0; i < 4; ++i) acc[i] = (f32x4)0.f;
      #pragma unroll
      for (int kt = 0; kt < KT_IN; ++kt) {
        #pragma unroll
        for (int i = 0; i < 4; ++i) {
          int ntg = wid*8 + g*4 + i;
          short8 bfr = *(const short8*)(ws + ((ntg*KT_IN + kt)*64 + lane)*8);
          acc[i] = __builtin_amdgcn_mfma_f32_16x16x32_bf16(afr[kt], bfr, acc[i], 0, 0, 0);
        }
      }
      #pragma unroll
      for (int i = 0; i < 4; ++i) {
        int ntg = wid*8 + g*4 + i;
        u16* dst = (ntg < 24) ? sm.u : sm.z;
        int col = ((ntg < 24) ? ntg*16 : (ntg-24)*16) + l16;
        #pragma unroll
        for (int r = 0; r < 4; ++r)
          dst[(quad*4 + r)*DINP + col] = f2bf(acc[i][r]);
      }
    }
  }
  __syncthreads();

  // ---- P3: causal depthwise conv (k=4) + SiLU, thread = channel d ----
  {
    const int d = tid;
    float uv[TDIM];
    #pragma unroll
    for (int t = 0; t < TDIM; ++t) uv[t] = bf2f(sm.u[t*DINP + d]);
    float w0 = ldg<B16>(conv_w, d*4+0), w1 = ldg<B16>(conv_w, d*4+1);
    float w2 = ldg<B16>(conv_w, d*4+2), w3 = ldg<B16>(conv_w, d*4+3);
    float bias = ldg<B16>(conv_b, d);
    #pragma unroll
    for (int t = 0; t < TDIM; ++t) {
      float s = bias + uv[t]*w3;
      if (t >= 1) s += uv[t-1]*w2;
      if (t >= 2) s += uv[t-2]*w1;
      if (t >= 3) s += uv[t-3]*w0;
      sm.u[t*DINP + d] = f2bf(s * sigmoid_f(s));
    }
  }

  // hoist scan parameters (pure global loads; waves 3..5 idle in P4 anyway)
  float wd[RNK], A2[SDIM];
  float dt_bias = ldg<B16>(dt_proj_b, tid);
  #pragma unroll
  for (int r = 0; r < RNK; ++r) wd[r] = ldg<B16>(dt_proj_w, r*DIN + tid);
  #pragma unroll
  for (int s = 0; s < SDIM; ++s)
    A2[s] = -LOG2E * ex2(LOG2E * ldg<B16>(A_log, tid*SDIM + s));  // log2e * A
  float Dv = ldg<B16>(Dp, tid);
  __syncthreads();

  // ---- P4: x_proj via MFMA: waves 0..2, one 16-col tile each ----
  if (wid < 3) {
    f32x4 acc = (f32x4)0.f;
    #pragma unroll
    for (int kt = 0; kt < KT_XP; ++kt) {
      short8 afr = *(const short8*)(sm.u + l16*DINP + kt*32 + quad*8);
      short8 bfr = *(const short8*)(ws + OFF_XP + ((wid*KT_XP + kt)*64 + lane)*8);
      acc = __builtin_amdgcn_mfma_f32_16x16x32_bf16(afr, bfr, acc, 0, 0, 0);
    }
    #pragma unroll
    for (int r = 0; r < 4; ++r)
      sm.dbl[(quad*4 + r)*DBLP + wid*16 + l16] = acc[r];
  }
  __syncthreads();

  // ---- P5: dt_proj + softplus + selective scan + D skip + SiLU(z) gating ----
  {
    const int d = tid;
    float h[SDIM];
    #pragma unroll
    for (int s = 0; s < SDIM; ++s) h[s] = 0.f;
    for (int t = 0; t < TDIM; ++t) {
      float a = dt_bias;
      #pragma unroll
      for (int r = 0; r < RNK; ++r) a += sm.dbl[t*DBLP + r] * wd[r];
      float dtv = softplus_f(a);
      float uv  = bf2f(sm.u[t*DINP + d]);
      float du  = dtv * uv;
      float y = 0.f;
      #pragma unroll
      for (int s = 0; s < SDIM; ++s) {
        float dA = ex2(dtv * A2[s]);                   // exp(dt*A)
        h[s] = h[s]*dA + du * sm.dbl[t*DBLP + 12 + s]; // B_t[s] (broadcast)
        y += h[s] * sm.dbl[t*DBLP + 28 + s];           // C_t[s]
      }
      y += uv * Dv;
      float zv = bf2f(sm.z[t*DINP + d]);
      sm.z[t*DINP + d] = f2bf(y * (zv * sigmoid_f(zv)));  // gated y, in place
    }
  }
  __syncthreads();

  // ---- P6: out_proj via MFMA + residual (x re-read, L2/L3-hot) ----
  {
    f32x4 acc[2];
    acc[0] = (f32x4)0.f; acc[1] = (f32x4)0.f;
    #pragma unroll
    for (int kt = 0; kt < KT_OUT; ++kt) {
      short8 afr = *(const short8*)(sm.z + l16*DINP + kt*32 + quad*8);
      #pragma unroll
      for (int i = 0; i < 2; ++i) {
        int ntg = wid*2 + i;
        short8 bfr = *(const short8*)(ws + OFF_OUT + ((ntg*KT_OUT + kt)*64 + lane)*8);
        acc[i] = __builtin_amdgcn_mfma_f32_16x16x32_bf16(afr, bfr, acc[i], 0, 0, 0);
      }
    }
    #pragma unroll
    for (int i = 0; i < 2; ++i) {
      int col = (wid*2 + i)*16 + l16;
      #pragma unroll
      for (int r = 0; r < 4; ++r) {
        int row = quad*4 + r;
        int gi = ((b*TDIM + row)*HW784 + hw)*CDIM + col;
        float o = ldg<B16>(x, gi) + acc[i][r];
        stg<B16>(out, gi, o);
      }
    }
  }
}

__launch_bounds__(384, 6)   // 6 waves/EU -> 4 blocks/CU; caps VGPR at ~85
__global__ void mamba_mfma(
    const u16* __restrict__ ws,
    const void* __restrict__ x,        const void* __restrict__ norm_w,
    const void* __restrict__ conv_w,   const void* __restrict__ conv_b,
    const void* __restrict__ dt_proj_w,const void* __restrict__ dt_proj_b,
    const void* __restrict__ A_log,    const void* __restrict__ Dp,
    void* __restrict__ out)
{
  __shared__ Smem sm;
  if (probe_bf16(x))
    body<true >(sm, ws, x, norm_w, conv_w, conv_b, dt_proj_w, dt_proj_b, A_log, Dp, out);
  else
    body<false>(sm, ws, x, norm_w, conv_w, conv_b, dt_proj_w, dt_proj_b, A_log, Dp, out);
}

// ---------------- fallback (round-2 kernel, no ws needed) -------------------
struct SmemF {
  float dt [TDIM*DIN];
  float dbl[TDIM*DBLW];
  u16   xs [TDIM*CDIM];
  u16   xn [TDIM*CDIM];
  u16   u  [TDIM*DIN];
  u16   z  [TDIM*DIN];
};

template<bool B16>
__device__ __forceinline__ void body_fb(
    SmemF& sm,
    const void* __restrict__ x,        const void* __restrict__ norm_w,
    const void* __restrict__ in_proj_w,const void* __restrict__ conv_w,
    const void* __restrict__ conv_b,   const void* __restrict__ x_proj_w,
    const void* __restrict__ dt_proj_w,const void* __restrict__ dt_proj_b,
    const void* __restrict__ A_log,    const void* __restrict__ Dp,
    const void* __restrict__ out_proj_w, void* __restrict__ out)
{
  const int tid = threadIdx.x;
  const int n  = blockIdx.x;
  const int b  = n / HW784;
  const int hw = n - b * HW784;

  for (int i = tid; i < TDIM*CDIM; i += 384) {
    int t = i / CDIM, c = i - t * CDIM;
    sm.xs[i] = f2bf(ldg<B16>(x, ((b*TDIM + t)*HW784 + hw)*CDIM + c));
  }
  __syncthreads();
  {
    int wave = tid >> 6, lane = tid & 63;
    for (int t = wave; t < TDIM; t += 6) {
      float ss = 0.f;
      for (int c = lane; c < CDIM; c += 64) {
        float v = bf2f(sm.xs[t*CDIM + c]); ss += v*v;
      }
      #pragma unroll
      for (int off = 32; off > 0; off >>= 1) ss += __shfl_xor(ss, off, 64);
      float rs = rsqrtf(ss * (1.0f/CDIM) + 1e-6f);
      for (int c = lane; c < CDIM; c += 64)
        sm.xn[t*CDIM + c] = f2bf(bf2f(sm.xs[t*CDIM + c]) * rs * ldg<B16>(norm_w, c));
    }
  }
  __syncthreads();
  {
    float acc0[TDIM], acc1[TDIM];
    #pragma unroll
    for (int t = 0; t < TDIM; ++t) { acc0[t] = 0.f; acc1[t] = 0.f; }
    const int j0 = 2 * tid;
    for (int c = 0; c < CDIM; c += 2) {
      float wA0 = ldg<B16>(in_proj_w,  c   *XZW + j0);
      float wA1 = ldg<B16>(in_proj_w,  c   *XZW + j0 + 1);
      float wB0 = ldg<B16>(in_proj_w, (c+1)*XZW + j0);
      float wB1 = ldg<B16>(in_proj_w, (c+1)*XZW + j0 + 1);
      #pragma unroll
      for (int t = 0; t < TDIM; ++t) {
        u32 xv = *(const u32*)(sm.xn + t*CDIM + c);
        float x0 = asf(xv << 16), x1 = asf(xv & 0xFFFF0000u);
        acc0[t] += x0*wA0 + x1*wB0;
        acc1[t] += x0*wA1 + x1*wB1;
      }
    }
    if (tid < 192) {
      #pragma unroll
      for (int t = 0; t < TDIM; ++t) {
        sm.u[t*DIN + j0]   = f2bf(acc0[t]);
        sm.u[t*DIN + j0+1] = f2bf(acc1[t]);
      }
    } else {
      int z0 = j0 - 384;
      #pragma unroll
      for (int t = 0; t < TDIM; ++t) {
        sm.z[t*DIN + z0]   = f2bf(acc0[t]);
        sm.z[t*DIN + z0+1] = f2bf(acc1[t]);
      }
    }
  }
  __syncthreads();
  {
    const int d = tid;
    float uv[TDIM];
    #pragma unroll
    for (int t = 0; t < TDIM; ++t) uv[t] = bf2f(sm.u[t*DIN + d]);
    float w0 = ldg<B16>(conv_w, d*4+0), w1 = ldg<B16>(conv_w, d*4+1);
    float w2 = ldg<B16>(conv_w, d*4+2), w3 = ldg<B16>(conv_w, d*4+3);
    float bias = ldg<B16>(conv_b, d);
    #pragma unroll
    for (int t = 0; t < TDIM; ++t) {
      float s = bias + uv[t]*w3;
      if (t >= 1) s += uv[t-1]*w2;
      if (t >= 2) s += uv[t-2]*w1;
      if (t >= 3) s += uv[t-3]*w0;
      float sg = 1.0f / (1.0f + __expf(-s));
      sm.u[t*DIN + d] = f2bf(s * sg);
    }
  }
  __syncthreads();
  for (int o = tid; o < TDIM*DBLW; o += 384) {
    int t = o / DBLW, j = o - t*DBLW;
    float acc = 0.f;
    for (int d = 0; d < DIN; ++d)
      acc += bf2f(sm.u[t*DIN + d]) * ldg<B16>(x_proj_w, d*DBLW + j);
    sm.dbl[o] = acc;
  }
  __syncthreads();
  {
    const int d = tid;
    float wd[RNK];
    #pragma unroll
    for (int r = 0; r < RNK; ++r) wd[r] = ldg<B16>(dt_proj_w, r*DIN + d);
    float bias = ldg<B16>(dt_proj_b, d);
    #pragma unroll
    for (int t = 0; t < TDIM; ++t) {
      float a = bias;
      #pragma unroll
      for (int r = 0; r < RNK; ++r) a += sm.dbl[t*DBLW + r] * wd[r];
      sm.dt[t*DIN + d] = fmaxf(a, 0.f) + log1pf(__expf(-fabsf(a)));
    }
  }
  __syncthreads();
  {
    const int d = tid;
    float A[SDIM], h[SDIM];
    #pragma unroll
    for (int s = 0; s < SDIM; ++s) {
      A[s] = -__expf(ldg<B16>(A_log, d*SDIM + s));
      h[s] = 0.f;
    }
    float Dv = ldg<B16>(Dp, d);
    for (int t = 0; t < TDIM; ++t) {
      float dtv = sm.dt[t*DIN + d];
      float uv  = bf2f(sm.u[t*DIN + d]);
      float du  = dtv * uv;
      float y = 0.f;
      #pragma unroll
      for (int s = 0; s < SDIM; ++s) {
        float dA = __expf(dtv * A[s]);
        h[s] = h[s]*dA + du * sm.dbl[t*DBLW + 12 + s];
        y += h[s] * sm.dbl[t*DBLW + 28 + s];
      }
      y += uv * Dv;
      float zv = bf2f(sm.z[t*DIN + d]);
      float sg = 1.0f / (1.0f + __expf(-zv));
      sm.dt[t*DIN + d] = y * (zv * sg);
    }
  }
  __syncthreads();
  {
    const int tt = tid / CDIM;
    const int c  = tid - tt*CDIM;
    float acc[8];
    #pragma unroll
    for (int i = 0; i < 8; ++i) acc[i] = 0.f;
    for (int d = 0; d < DIN; ++d) {
      float w = ldg<B16>(out_proj_w, d*CDIM + c);
      #pragma unroll
      for (int i = 0; i < 8; ++i)
        acc[i] += sm.dt[(tt*8 + i)*DIN + d] * w;
    }
    #pragma unroll
    for (int i = 0; i < 8; ++i) {
      int t = tt*8 + i;
      float o = bf2f(sm.xs[t*CDIM + c]) + acc[i];
      stg<B16>(out, ((b*TDIM + t)*HW784 + hw)*CDIM + c, o);
    }
  }
}

__launch_bounds__(384)
__global__ void mamba_fallback(
    const void* __restrict__ x,        const void* __restrict__ norm_w,
    const void* __restrict__ in_proj_w,const void* __restrict__ conv_w,
    const void* __restrict__ conv_b,   const void* __restrict__ x_proj_w,
    const void* __restrict__ dt_proj_w,const void* __restrict__ dt_proj_b,
    const void* __restrict__ A_log,    const void* __restrict__ Dp,
    const void* __restrict__ out_proj_w, void* __restrict__ out)
{
  __shared__ SmemF sm;
  if (probe_bf16(x))
    body_fb<true >(sm, x, norm_w, in_proj_w, conv_w, conv_b, x_proj_w,
                   dt_proj_w, dt_proj_b, A_log, Dp, out_proj_w, out);
  else
    body_fb<false>(sm, x, norm_w, in_proj_w, conv_w, conv_b, x_proj_w,
                   dt_proj_w, dt_proj_b, A_log, Dp, out_proj_w, out);
}

extern "C" void kernel_launch(void* const* d_in, const int* in_sizes, int n_in,
                              void* d_out, int out_size, void* d_ws, size_t ws_size,
                              hipStream_t stream) {
  if (ws_size >= WS_NEED) {
    int packThreads = GRP_IN + GRP_OUT + GRP_XP;
    pack_w<<<(packThreads + 255) / 256, 256, 0, stream>>>(
        d_in[0], d_in[2], d_in[10], d_in[5], (u16*)d_ws);
    mamba_mfma<<<NSEQ, 384, 0, stream>>>(
        (const u16*)d_ws,
        d_in[0], d_in[1], d_in[3], d_in[4],
        d_in[6], d_in[7], d_in[8], d_in[9], d_out);
  } else {
    mamba_fallback<<<NSEQ, 384, 0, stream>>>(
        d_in[0], d_in[1], d_in[2], d_in[3], d_in[4], d_in[5],
        d_in[6], d_in[7], d_in[8], d_in[9], d_in[10], d_out);
  }
}

// Round 5
// 170.926 us; speedup vs baseline: 4.3630x; 1.0873x over previous
//
#include <hip/hip_runtime.h>

// TemporalMambaBlock: B=2,T=16,H=W=28,C=192; D_inner=384, d_state=16, dt_rank=12, d_conv=4
#define NSEQ 1568
#define TDIM 16
#define CDIM 192
#define DIN  384
#define SDIM 16
#define RNK  12
#define XZW  768
#define DBLW 44
#define HW784 784

// padded LDS strides (halves): row stride dwords mod 32 == 4 -> b128 quad reads 2-way (free),
// and row byte-stride % 16 == 0 keeps ds_read_b128 aligned.
#define XNP  200   // xn rows (192 + 8 pad)  -> 400 B
#define DINP 392   // u / z rows (384 + 8)   -> 784 B
#define DBLP 48    // dbl rows (44 -> 48, f32)

// packed-weight tiling (B-fragment order for mfma_f32_16x16x32_bf16)
#define NT_IN 48
#define KT_IN 6
#define NT_OUT 12
#define KT_OUT 12
#define NT_XP 3
#define KT_XP 12
#define GRP_IN  (NT_IN*KT_IN*64)    // 18432 groups of 8
#define GRP_OUT (NT_OUT*KT_OUT*64)  // 9216
#define GRP_XP  (NT_XP*KT_XP*64)    // 2304
#define OFF_OUT (GRP_IN*8)
#define OFF_XP  (OFF_OUT + GRP_OUT*8)
#define WS_NEED ((size_t)(OFF_XP + GRP_XP*8) * 2)  // 479232 bytes

#define IN_EL  (CDIM*XZW)   // 147456
#define OUT_EL (DIN*CDIM)   // 73728
#define XP_EL  (GRP_XP*8)   // 18432 (packed space, incl. pad)
#define PACK_TOT (IN_EL + OUT_EL + XP_EL)

typedef unsigned short u16;
typedef unsigned int   u32;
typedef __attribute__((ext_vector_type(8))) short short8;
typedef __attribute__((ext_vector_type(4))) float f32x4;

#define LOG2E 1.44269504f
#define LN2   0.69314718f

__device__ __forceinline__ float bf2f(u16 u) {
  union { u32 i; float f; } c; c.i = ((u32)u) << 16; return c.f;
}
__device__ __forceinline__ u16 f2bf(float f) {   // round-to-nearest-even
  union { float f; u32 i; } c; c.f = f;
  u32 i = c.i;
  i += 0x7FFFu + ((i >> 16) & 1u);
  return (u16)(i >> 16);
}

// raw transcendental units (v_exp_f32 / v_log_f32 / v_rcp_f32)
__device__ __forceinline__ float ex2(float x) {
#if __has_builtin(__builtin_amdgcn_exp2f)
  return __builtin_amdgcn_exp2f(x);
#else
  return exp2f(x);
#endif
}
__device__ __forceinline__ float lg2(float x) {
#if __has_builtin(__builtin_amdgcn_logf)
  return __builtin_amdgcn_logf(x);
#else
  return log2f(x);
#endif
}
__device__ __forceinline__ float frcp(float x) {
#if __has_builtin(__builtin_amdgcn_rcpf)
  return __builtin_amdgcn_rcpf(x);
#else
  return 1.0f / x;
#endif
}
__device__ __forceinline__ float sigmoid_f(float s) {       // 1/(1+e^-s)
  return frcp(1.0f + ex2(-LOG2E * s));
}
__device__ __forceinline__ float softplus_f(float a) {      // log(1+e^a), stable
  return fmaxf(a, 0.f) + LN2 * lg2(1.0f + ex2(-LOG2E * fabsf(a)));
}

template<bool B16>
__device__ __forceinline__ float ldg(const void* p, int i) {
  if (B16) return bf2f(((const u16*)p)[i]);
  return ((const float*)p)[i];
}
template<bool B16>
__device__ __forceinline__ void stg(void* p, int i, float v) {
  if (B16) ((u16*)p)[i] = f2bf(v);
  else     ((float*)p)[i] = v;
}

// dtype probe: bf16 data has plausible exponents at even u16 slots; f32 read
// as u16 gives mantissa noise. (Round-2/3/4 evidence: selects the f32 path.)
__device__ __forceinline__ bool probe_bf16(const void* x) {
  const u16* xu = (const u16*)x;
  int plaus = 0;
  #pragma unroll
  for (int k = 0; k < 32; ++k) {
    u16 v = xu[2*k];
    int e = (v >> 7) & 0xFF;
    plaus += ((e >= 100 && e <= 140) || v == 0) ? 1 : 0;
  }
  return plaus >= 16;
}

// ---------------- weight packing: element-wise, coalesced reads -------------
// packed[((nt*KT + kt)*64 + lane)*8 + j] = W[kt*32 + (lane>>4)*8 + j][nt*16 + (lane&15)]
template<bool B16>
__device__ __forceinline__ void pack_body(const void* in_w, const void* out_w,
                                          const void* xp_w, u16* ws, int e) {
  if (e < IN_EL) {                       // one thread per source element, coalesced read
    int k = e / XZW, n = e - k*XZW;
    int nt = n >> 4, l16 = n & 15, kt = k >> 5, q8 = (k & 31) >> 3, j = k & 7;
    int lane = q8*16 + l16;
    ws[((nt*KT_IN + kt)*64 + lane)*8 + j] = f2bf(ldg<B16>(in_w, e));
  } else if (e < IN_EL + OUT_EL) {
    int ee = e - IN_EL;
    int k = ee / CDIM, n = ee - k*CDIM;
    int nt = n >> 4, l16 = n & 15, kt = k >> 5, q8 = (k & 31) >> 3, j = k & 7;
    int lane = q8*16 + l16;
    ws[OFF_OUT + ((nt*KT_OUT + kt)*64 + lane)*8 + j] = f2bf(ldg<B16>(out_w, ee));
  } else if (e < PACK_TOT) {             // xp: iterate packed space (handles pad)
    int ee = e - IN_EL - OUT_EL;
    int gg = ee >> 3, j = ee & 7;
    int lane = gg & 63, kt = (gg >> 6) % KT_XP, nt = gg / (64*KT_XP);
    int k = kt*32 + (lane >> 4)*8 + j, n = nt*16 + (lane & 15);
    ws[OFF_XP + ee] = f2bf(n < DBLW ? ldg<B16>(xp_w, k*DBLW + n) : 0.f);
  }
}

__global__ void pack_w(const void* __restrict__ x, const void* __restrict__ in_w,
                       const void* __restrict__ out_w, const void* __restrict__ xp_w,
                       u16* __restrict__ ws) {
  int e = blockIdx.x * blockDim.x + threadIdx.x;
  if (probe_bf16(x)) pack_body<true >(in_w, out_w, xp_w, ws, e);
  else               pack_body<false>(in_w, out_w, xp_w, ws, e);
}

// ---------------- fused MFMA kernel -----------------------------------------
struct Smem {
  float dbl[TDIM*DBLP];   // x_proj out: dt_low|B|C        3072 B (16B-aligned rows)
  u16   xn [TDIM*XNP];    // rmsnormed, padded             6400 B
  u16   u  [TDIM*DINP];   // u -> uc (in-place), padded   12544 B
  u16   z  [TDIM*DINP];   // z -> gated y (in-place)      12544 B
};                        // total 34,560 B -> 4 blocks/CU

template<bool B16>
__device__ __forceinline__ void body(
    Smem& sm, const u16* __restrict__ ws,
    const void* __restrict__ x,        const void* __restrict__ norm_w,
    const void* __restrict__ conv_w,   const void* __restrict__ conv_b,
    const void* __restrict__ dt_proj_w,const void* __restrict__ dt_proj_b,
    const void* __restrict__ A_log,    const void* __restrict__ Dp,
    void* __restrict__ out)
{
  const int tid  = threadIdx.x;
  const int wid  = tid >> 6;
  const int lane = tid & 63;
  const int quad = lane >> 4;
  const int l16  = lane & 15;
  const int n  = blockIdx.x;
  const int b  = n / HW784;
  const int hw = n - b * HW784;

  // ---- P1: RMSNorm straight from global (192 = 3 x 64 lanes) -> xn ----
  {
    const int c0 = lane, c1 = lane + 64, c2 = lane + 128;
    float nw0 = ldg<B16>(norm_w, c0), nw1 = ldg<B16>(norm_w, c1), nw2 = ldg<B16>(norm_w, c2);
    for (int t = wid; t < TDIM; t += 6) {
      int base = ((b*TDIM + t)*HW784 + hw)*CDIM;
      float v0 = ldg<B16>(x, base + c0);
      float v1 = ldg<B16>(x, base + c1);
      float v2 = ldg<B16>(x, base + c2);
      float ss = v0*v0 + v1*v1 + v2*v2;
      #pragma unroll
      for (int off = 32; off > 0; off >>= 1) ss += __shfl_xor(ss, off, 64);
      float rs = rsqrtf(ss * (1.0f/CDIM) + 1e-6f);
      sm.xn[t*XNP + c0] = f2bf(v0 * rs * nw0);
      sm.xn[t*XNP + c1] = f2bf(v1 * rs * nw1);
      sm.xn[t*XNP + c2] = f2bf(v2 * rs * nw2);
    }
  }
  __syncthreads();

  // ---- P2: in_proj via MFMA: wave w -> col tiles w*8..w*8+7 (2 groups of 4) ----
  {
    short8 afr[KT_IN];
    #pragma unroll
    for (int kt = 0; kt < KT_IN; ++kt)
      afr[kt] = *(const short8*)(sm.xn + l16*XNP + kt*32 + quad*8);
    #pragma unroll
    for (int g = 0; g < 2; ++g) {
      f32x4 acc[4];
      #pragma unroll
      for (int i = 0; i < 4; ++i) acc[i] = (f32x4)0.f;
      #pragma unroll
      for (int kt = 0; kt < KT_IN; ++kt) {
        #pragma unroll
        for (int i = 0; i < 4; ++i) {
          int ntg = wid*8 + g*4 + i;
          short8 bfr = *(const short8*)(ws + ((ntg*KT_IN + kt)*64 + lane)*8);
          acc[i] = __builtin_amdgcn_mfma_f32_16x16x32_bf16(afr[kt], bfr, acc[i], 0, 0, 0);
        }
      }
      #pragma unroll
      for (int i = 0; i < 4; ++i) {
        int ntg = wid*8 + g*4 + i;
        u16* dst = (ntg < 24) ? sm.u : sm.z;
        int col = ((ntg < 24) ? ntg*16 : (ntg-24)*16) + l16;
        #pragma unroll
        for (int r = 0; r < 4; ++r)
          dst[(quad*4 + r)*DINP + col] = f2bf(acc[i][r]);
      }
    }
  }
  __syncthreads();

  // ---- P3: causal depthwise conv (k=4) + SiLU, thread = channel d ----
  {
    const int d = tid;
    float w0 = ldg<B16>(conv_w, d*4+0), w1 = ldg<B16>(conv_w, d*4+1);
    float w2 = ldg<B16>(conv_w, d*4+2), w3 = ldg<B16>(conv_w, d*4+3);
    float bias = ldg<B16>(conv_b, d);
    float um1 = 0.f, um2 = 0.f, um3 = 0.f;
    #pragma unroll
    for (int t = 0; t < TDIM; ++t) {
      float cur = bf2f(sm.u[t*DINP + d]);
      float s = bias + cur*w3 + um1*w2 + um2*w1 + um3*w0;
      um3 = um2; um2 = um1; um1 = cur;
      sm.u[t*DINP + d] = f2bf(s * sigmoid_f(s));
    }
  }

  // hoist scan parameters (pure global loads; waves 3..5 idle in P4 anyway)
  float wd[RNK];
  float dt_bias = ldg<B16>(dt_proj_b, tid);
  #pragma unroll
  for (int r = 0; r < RNK; ++r) wd[r] = ldg<B16>(dt_proj_w, r*DIN + tid);
  float Dv = ldg<B16>(Dp, tid);
  // geometric-A detection: A[s] = -exp(A_log[s]); geo iff A[s] == (s+1)*A[0]
  float a2;                 // LOG2E * A[0]  (negative)
  bool geo;
  {
    a2 = -LOG2E * ex2(LOG2E * ldg<B16>(A_log, tid*SDIM + 0));
    geo = true;
    #pragma unroll
    for (int s = 1; s < SDIM; ++s) {
      float as = -LOG2E * ex2(LOG2E * ldg<B16>(A_log, tid*SDIM + s));
      geo = geo && (fabsf(as - (float)(s+1)*a2) <= 1e-4f * fabsf(as) + 1e-30f);
    }
  }
  __syncthreads();

  // ---- P4: x_proj via MFMA: waves 0..2, one 16-col tile each ----
  if (wid < 3) {
    f32x4 acc = (f32x4)0.f;
    #pragma unroll
    for (int kt = 0; kt < KT_XP; ++kt) {
      short8 afr = *(const short8*)(sm.u + l16*DINP + kt*32 + quad*8);
      short8 bfr = *(const short8*)(ws + OFF_XP + ((wid*KT_XP + kt)*64 + lane)*8);
      acc = __builtin_amdgcn_mfma_f32_16x16x32_bf16(afr, bfr, acc, 0, 0, 0);
    }
    #pragma unroll
    for (int r = 0; r < 4; ++r)
      sm.dbl[(quad*4 + r)*DBLP + wid*16 + l16] = acc[r];
  }
  __syncthreads();

  // ---- P5: dt_proj + softplus + selective scan + D skip + SiLU(z) gating ----
  {
    const int d = tid;
    float h[SDIM];
    #pragma unroll
    for (int s = 0; s < SDIM; ++s) h[s] = 0.f;
    if (geo) {
      for (int t = 0; t < TDIM; ++t) {
        const float* row = sm.dbl + t*DBLP;
        f32x4 d0 = *(const f32x4*)(row + 0);
        f32x4 d1 = *(const f32x4*)(row + 4);
        f32x4 d2 = *(const f32x4*)(row + 8);
        float a = dt_bias
          + d0[0]*wd[0] + d0[1]*wd[1] + d0[2]*wd[2]  + d0[3]*wd[3]
          + d1[0]*wd[4] + d1[1]*wd[5] + d1[2]*wd[6]  + d1[3]*wd[7]
          + d2[0]*wd[8] + d2[1]*wd[9] + d2[2]*wd[10] + d2[3]*wd[11];
        float dtv = softplus_f(a);
        float uv  = bf2f(sm.u[t*DINP + d]);
        float du  = dtv * uv;
        float q = ex2(dtv * a2);               // dA[0] = exp(dt*A[0])
        float Pq[SDIM];                        // Pq[s] = q^(s+1), log-depth tree
        Pq[0] = q;        Pq[1] = q*q;       Pq[2] = Pq[1]*q;     Pq[3] = Pq[1]*Pq[1];
        Pq[4] = Pq[3]*q;  Pq[5] = Pq[3]*Pq[1]; Pq[6] = Pq[3]*Pq[2]; Pq[7] = Pq[3]*Pq[3];
        Pq[8] = Pq[7]*q;  Pq[9] = Pq[7]*Pq[1]; Pq[10]= Pq[7]*Pq[2]; Pq[11]= Pq[7]*Pq[3];
        Pq[12]= Pq[7]*Pq[4]; Pq[13]= Pq[7]*Pq[5]; Pq[14]= Pq[7]*Pq[6]; Pq[15]= Pq[7]*Pq[7];
        float y = 0.f;
        #pragma unroll
        for (int g = 0; g < 4; ++g) {
          f32x4 Bv = *(const f32x4*)(row + 12 + 4*g);
          f32x4 Cv = *(const f32x4*)(row + 28 + 4*g);
          #pragma unroll
          for (int j = 0; j < 4; ++j) {
            int s = 4*g + j;
            h[s] = h[s]*Pq[s] + du*Bv[j];
            y += h[s]*Cv[j];
          }
        }
        y += uv * Dv;
        float zv = bf2f(sm.z[t*DINP + d]);
        sm.z[t*DINP + d] = f2bf(y * (zv * sigmoid_f(zv)));
      }
    } else {
      float A2[SDIM];
      #pragma unroll
      for (int s = 0; s < SDIM; ++s)
        A2[s] = -LOG2E * ex2(LOG2E * ldg<B16>(A_log, d*SDIM + s));
      for (int t = 0; t < TDIM; ++t) {
        const float* row = sm.dbl + t*DBLP;
        f32x4 d0 = *(const f32x4*)(row + 0);
        f32x4 d1 = *(const f32x4*)(row + 4);
        f32x4 d2 = *(const f32x4*)(row + 8);
        float a = dt_bias
          + d0[0]*wd[0] + d0[1]*wd[1] + d0[2]*wd[2]  + d0[3]*wd[3]
          + d1[0]*wd[4] + d1[1]*wd[5] + d1[2]*wd[6]  + d1[3]*wd[7]
          + d2[0]*wd[8] + d2[1]*wd[9] + d2[2]*wd[10] + d2[3]*wd[11];
        float dtv = softplus_f(a);
        float uv  = bf2f(sm.u[t*DINP + d]);
        float du  = dtv * uv;
        float y = 0.f;
        #pragma unroll
        for (int g = 0; g < 4; ++g) {
          f32x4 Bv = *(const f32x4*)(row + 12 + 4*g);
          f32x4 Cv = *(const f32x4*)(row + 28 + 4*g);
          #pragma unroll
          for (int j = 0; j < 4; ++j) {
            int s = 4*g + j;
            float dA = ex2(dtv * A2[s]);
            h[s] = h[s]*dA + du*Bv[j];
            y += h[s]*Cv[j];
          }
        }
        y += uv * Dv;
        float zv = bf2f(sm.z[t*DINP + d]);
        sm.z[t*DINP + d] = f2bf(y * (zv * sigmoid_f(zv)));
      }
    }
  }
  __syncthreads();

  // ---- P6: out_proj via MFMA + residual (x re-read, L2/L3-hot) ----
  {
    f32x4 acc[2];
    acc[0] = (f32x4)0.f; acc[1] = (f32x4)0.f;
    #pragma unroll
    for (int kt = 0; kt < KT_OUT; ++kt) {
      short8 afr = *(const short8*)(sm.z + l16*DINP + kt*32 + quad*8);
      #pragma unroll
      for (int i = 0; i < 2; ++i) {
        int ntg = wid*2 + i;
        short8 bfr = *(const short8*)(ws + OFF_OUT + ((ntg*KT_OUT + kt)*64 + lane)*8);
        acc[i] = __builtin_amdgcn_mfma_f32_16x16x32_bf16(afr, bfr, acc[i], 0, 0, 0);
      }
    }
    #pragma unroll
    for (int i = 0; i < 2; ++i) {
      int col = (wid*2 + i)*16 + l16;
      #pragma unroll
      for (int r = 0; r < 4; ++r) {
        int row = quad*4 + r;
        int gi = ((b*TDIM + row)*HW784 + hw)*CDIM + col;
        float o = ldg<B16>(x, gi) + acc[i][r];
        stg<B16>(out, gi, o);
      }
    }
  }
}

__launch_bounds__(384, 6)   // 6 waves/EU -> 4 blocks/CU; caps VGPR at ~85
__global__ void mamba_mfma(
    const u16* __restrict__ ws,
    const void* __restrict__ x,        const void* __restrict__ norm_w,
    const void* __restrict__ conv_w,   const void* __restrict__ conv_b,
    const void* __restrict__ dt_proj_w,const void* __restrict__ dt_proj_b,
    const void* __restrict__ A_log,    const void* __restrict__ Dp,
    void* __restrict__ out)
{
  __shared__ Smem sm;
  if (probe_bf16(x))
    body<true >(sm, ws, x, norm_w, conv_w, conv_b, dt_proj_w, dt_proj_b, A_log, Dp, out);
  else
    body<false>(sm, ws, x, norm_w, conv_w, conv_b, dt_proj_w, dt_proj_b, A_log, Dp, out);
}

// ---------------- fallback (round-2 kernel, no ws needed) -------------------
struct SmemF {
  float dt [TDIM*DIN];
  float dbl[TDIM*DBLW];
  u16   xs [TDIM*CDIM];
  u16   xn [TDIM*CDIM];
  u16   u  [TDIM*DIN];
  u16   z  [TDIM*DIN];
};

template<bool B16>
__device__ __forceinline__ void body_fb(
    SmemF& sm,
    const void* __restrict__ x,        const void* __restrict__ norm_w,
    const void* __restrict__ in_proj_w,const void* __restrict__ conv_w,
    const void* __restrict__ conv_b,   const void* __restrict__ x_proj_w,
    const void* __restrict__ dt_proj_w,const void* __restrict__ dt_proj_b,
    const void* __restrict__ A_log,    const void* __restrict__ Dp,
    const void* __restrict__ out_proj_w, void* __restrict__ out)
{
  const int tid = threadIdx.x;
  const int n  = blockIdx.x;
  const int b  = n / HW784;
  const int hw = n - b * HW784;

  for (int i = tid; i < TDIM*CDIM; i += 384) {
    int t = i / CDIM, c = i - t * CDIM;
    sm.xs[i] = f2bf(ldg<B16>(x, ((b*TDIM + t)*HW784 + hw)*CDIM + c));
  }
  __syncthreads();
  {
    int wave = tid >> 6, lane = tid & 63;
    for (int t = wave; t < TDIM; t += 6) {
      float ss = 0.f;
      for (int c = lane; c < CDIM; c += 64) {
        float v = bf2f(sm.xs[t*CDIM + c]); ss += v*v;
      }
      #pragma unroll
      for (int off = 32; off > 0; off >>= 1) ss += __shfl_xor(ss, off, 64);
      float rs = rsqrtf(ss * (1.0f/CDIM) + 1e-6f);
      for (int c = lane; c < CDIM; c += 64)
        sm.xn[t*CDIM + c] = f2bf(bf2f(sm.xs[t*CDIM + c]) * rs * ldg<B16>(norm_w, c));
    }
  }
  __syncthreads();
  {
    float acc0[TDIM], acc1[TDIM];
    #pragma unroll
    for (int t = 0; t < TDIM; ++t) { acc0[t] = 0.f; acc1[t] = 0.f; }
    const int j0 = 2 * tid;
    for (int c = 0; c < CDIM; c += 2) {
      float wA0 = ldg<B16>(in_proj_w,  c   *XZW + j0);
      float wA1 = ldg<B16>(in_proj_w,  c   *XZW + j0 + 1);
      float wB0 = ldg<B16>(in_proj_w, (c+1)*XZW + j0);
      float wB1 = ldg<B16>(in_proj_w, (c+1)*XZW + j0 + 1);
      #pragma unroll
      for (int t = 0; t < TDIM; ++t) {
        union { u32 i; float f; } c0, c1;
        u32 xv = *(const u32*)(sm.xn + t*CDIM + c);
        c0.i = xv << 16; c1.i = xv & 0xFFFF0000u;
        acc0[t] += c0.f*wA0 + c1.f*wB0;
        acc1[t] += c0.f*wA1 + c1.f*wB1;
      }
    }
    if (tid < 192) {
      #pragma unroll
      for (int t = 0; t < TDIM; ++t) {
        sm.u[t*DIN + j0]   = f2bf(acc0[t]);
        sm.u[t*DIN + j0+1] = f2bf(acc1[t]);
      }
    } else {
      int z0 = j0 - 384;
      #pragma unroll
      for (int t = 0; t < TDIM; ++t) {
        sm.z[t*DIN + z0]   = f2bf(acc0[t]);
        sm.z[t*DIN + z0+1] = f2bf(acc1[t]);
      }
    }
  }
  __syncthreads();
  {
    const int d = tid;
    float uv[TDIM];
    #pragma unroll
    for (int t = 0; t < TDIM; ++t) uv[t] = bf2f(sm.u[t*DIN + d]);
    float w0 = ldg<B16>(conv_w, d*4+0), w1 = ldg<B16>(conv_w, d*4+1);
    float w2 = ldg<B16>(conv_w, d*4+2), w3 = ldg<B16>(conv_w, d*4+3);
    float bias = ldg<B16>(conv_b, d);
    #pragma unroll
    for (int t = 0; t < TDIM; ++t) {
      float s = bias + uv[t]*w3;
      if (t >= 1) s += uv[t-1]*w2;
      if (t >= 2) s += uv[t-2]*w1;
      if (t >= 3) s += uv[t-3]*w0;
      float sg = 1.0f / (1.0f + __expf(-s));
      sm.u[t*DIN + d] = f2bf(s * sg);
    }
  }
  __syncthreads();
  for (int o = tid; o < TDIM*DBLW; o += 384) {
    int t = o / DBLW, j = o - t*DBLW;
    float acc = 0.f;
    for (int d = 0; d < DIN; ++d)
      acc += bf2f(sm.u[t*DIN + d]) * ldg<B16>(x_proj_w, d*DBLW + j);
    sm.dbl[o] = acc;
  }
  __syncthreads();
  {
    const int d = tid;
    float wd[RNK];
    #pragma unroll
    for (int r = 0; r < RNK; ++r) wd[r] = ldg<B16>(dt_proj_w, r*DIN + d);
    float bias = ldg<B16>(dt_proj_b, d);
    #pragma unroll
    for (int t = 0; t < TDIM; ++t) {
      float a = bias;
      #pragma unroll
      for (int r = 0; r < RNK; ++r) a += sm.dbl[t*DBLW + r] * wd[r];
      sm.dt[t*DIN + d] = fmaxf(a, 0.f) + log1pf(__expf(-fabsf(a)));
    }
  }
  __syncthreads();
  {
    const int d = tid;
    float A[SDIM], h[SDIM];
    #pragma unroll
    for (int s = 0; s < SDIM; ++s) {
      A[s] = -__expf(ldg<B16>(A_log, d*SDIM + s));
      h[s] = 0.f;
    }
    float Dv = ldg<B16>(Dp, d);
    for (int t = 0; t < TDIM; ++t) {
      float dtv = sm.dt[t*DIN + d];
      float uv  = bf2f(sm.u[t*DIN + d]);
      float du  = dtv * uv;
      float y = 0.f;
      #pragma unroll
      for (int s = 0; s < SDIM; ++s) {
        float dA = __expf(dtv * A[s]);
        h[s] = h[s]*dA + du * sm.dbl[t*DBLW + 12 + s];
        y += h[s] * sm.dbl[t*DBLW + 28 + s];
      }
      y += uv * Dv;
      float zv = bf2f(sm.z[t*DIN + d]);
      float sg = 1.0f / (1.0f + __expf(-zv));
      sm.dt[t*DIN + d] = y * (zv * sg);
    }
  }
  __syncthreads();
  {
    const int tt = tid / CDIM;
    const int c  = tid - tt*CDIM;
    float acc[8];
    #pragma unroll
    for (int i = 0; i < 8; ++i) acc[i] = 0.f;
    for (int d = 0; d < DIN; ++d) {
      float w = ldg<B16>(out_proj_w, d*CDIM + c);
      #pragma unroll
      for (int i = 0; i < 8; ++i)
        acc[i] += sm.dt[(tt*8 + i)*DIN + d] * w;
    }
    #pragma unroll
    for (int i = 0; i < 8; ++i) {
      int t = tt*8 + i;
      float o = bf2f(sm.xs[t*CDIM + c]) + acc[i];
      stg<B16>(out, ((b*TDIM + t)*HW784 + hw)*CDIM + c, o);
    }
  }
}

__launch_bounds__(384)
__global__ void mamba_fallback(
    const void* __restrict__ x,        const void* __restrict__ norm_w,
    const void* __restrict__ in_proj_w,const void* __restrict__ conv_w,
    const void* __restrict__ conv_b,   const void* __restrict__ x_proj_w,
    const void* __restrict__ dt_proj_w,const void* __restrict__ dt_proj_b,
    const void* __restrict__ A_log,    const void* __restrict__ Dp,
    const void* __restrict__ out_proj_w, void* __restrict__ out)
{
  __shared__ SmemF sm;
  if (probe_bf16(x))
    body_fb<true >(sm, x, norm_w, in_proj_w, conv_w, conv_b, x_proj_w,
                   dt_proj_w, dt_proj_b, A_log, Dp, out_proj_w, out);
  else
    body_fb<false>(sm, x, norm_w, in_proj_w, conv_w, conv_b, x_proj_w,
                   dt_proj_w, dt_proj_b, A_log, Dp, out_proj_w, out);
}

extern "C" void kernel_launch(void* const* d_in, const int* in_sizes, int n_in,
                              void* d_out, int out_size, void* d_ws, size_t ws_size,
                              hipStream_t stream) {
  if (ws_size >= WS_NEED) {
    pack_w<<<(PACK_TOT + 255) / 256, 256, 0, stream>>>(
        d_in[0], d_in[2], d_in[10], d_in[5], (u16*)d_ws);
    mamba_mfma<<<NSEQ, 384, 0, stream>>>(
        (const u16*)d_ws,
        d_in[0], d_in[1], d_in[3], d_in[4],
        d_in[6], d_in[7], d_in[8], d_in[9], d_out);
  } else {
    mamba_fallback<<<NSEQ, 384, 0, stream>>>(
        d_in[0], d_in[1], d_in[2], d_in[3], d_in[4], d_in[5],
        d_in[6], d_in[7], d_in[8], d_in[9], d_in[10], d_out);
  }
}